// Round 1
// baseline (411.429 us; speedup 1.0000x reference)
//
#include <hip/hip_runtime.h>
#include <stdint.h>

#define S_LEN 2048
#define HIDDEN 1024
#define NH 16
#define NKV 4
#define HD 64

typedef unsigned short u16;
typedef __attribute__((ext_vector_type(8))) short short8;
typedef __attribute__((ext_vector_type(4))) float f32x4;

__device__ __forceinline__ u16 f2b(float f) {
  uint32_t u = __float_as_uint(f);
  uint32_t r = u + 0x7fffu + ((u >> 16) & 1u);
  return (u16)(r >> 16);
}
__device__ __forceinline__ float b2f(u16 b) {
  return __uint_as_float(((uint32_t)b) << 16);
}

// ---------------- fp32 -> bf16 convert ----------------
__global__ __launch_bounds__(256) void f2b_kernel(const float* __restrict__ src,
                                                  u16* __restrict__ dst, int n) {
  int i = blockIdx.x * 256 + threadIdx.x;
  if (i < n) dst[i] = f2b(src[i]);
}

// ---------------- bf16 GEMM: C[m][n] = sum_k A[m][k]*B[n][k] ----------------
// A:[M][K] bf16 row-major, B:[N][K] bf16 row-major (i.e. C = A * B^T)
// 128x128 tile, BK=32, 4 waves (2x2 quadrants of 64x64), mfma 16x16x32 bf16.
template <int OUT_BF16>
__global__ __launch_bounds__(256) void gemm_bt(const u16* __restrict__ A,
                                               const u16* __restrict__ B,
                                               void* __restrict__ Cv,
                                               int M, int N, int K) {
  __shared__ u16 As[128][32];
  __shared__ u16 Bs[128][32];
  const int tid = threadIdx.x;
  const int wid = tid >> 6, lane = tid & 63;
  const int fr = lane & 15, fg = lane >> 4;
  const int m0 = blockIdx.x * 128, n0 = blockIdx.y * 128;
  const int wr = wid >> 1, wc = wid & 1;
  f32x4 acc[4][4] = {};

  for (int k0 = 0; k0 < K; k0 += 32) {
    __syncthreads();
#pragma unroll
    for (int i = 0; i < 2; ++i) {
      int c = tid + i * 256;
      int r = c >> 2, col = (c & 3) << 3;
      *reinterpret_cast<short8*>(&As[r][col]) =
          *reinterpret_cast<const short8*>(&A[(size_t)(m0 + r) * K + k0 + col]);
      *reinterpret_cast<short8*>(&Bs[r][col]) =
          *reinterpret_cast<const short8*>(&B[(size_t)(n0 + r) * K + k0 + col]);
    }
    __syncthreads();
    short8 a[4], b[4];
#pragma unroll
    for (int i = 0; i < 4; ++i) {
      a[i] = *reinterpret_cast<const short8*>(&As[wr * 64 + i * 16 + fr][fg * 8]);
      b[i] = *reinterpret_cast<const short8*>(&Bs[wc * 64 + i * 16 + fr][fg * 8]);
    }
#pragma unroll
    for (int i = 0; i < 4; ++i)
#pragma unroll
      for (int j = 0; j < 4; ++j)
        acc[i][j] = __builtin_amdgcn_mfma_f32_16x16x32_bf16(a[i], b[j], acc[i][j], 0, 0, 0);
  }

  const int rb = fg * 4;
#pragma unroll
  for (int i = 0; i < 4; ++i)
#pragma unroll
    for (int j = 0; j < 4; ++j) {
      const int row0 = m0 + wr * 64 + i * 16 + rb;
      const int col = n0 + wc * 64 + j * 16 + fr;
#pragma unroll
      for (int r = 0; r < 4; ++r) {
        size_t idx = (size_t)(row0 + r) * N + col;
        if (OUT_BF16) ((u16*)Cv)[idx] = f2b(acc[i][j][r]);
        else          ((float*)Cv)[idx] = acc[i][j][r];
      }
    }
}

// ---------------- per-head RMSNorm + RoPE + layout build ----------------
// qkv: [4096][1536] bf16 (cols 0..1023 Q, 1024..1279 K, 1280..1535 V)
// outputs: Qn [B*NH][S][64], Kn [B*NKV][S][64], Vt [B*NKV][64][S] (all bf16)
__global__ __launch_bounds__(256) void normrope(const u16* __restrict__ qkv,
                                                const int* __restrict__ pos_ids,
                                                const float* __restrict__ cosT,
                                                const float* __restrict__ sinT,
                                                const float* __restrict__ qw,
                                                const float* __restrict__ kw,
                                                u16* __restrict__ Qn,
                                                u16* __restrict__ Kn,
                                                u16* __restrict__ Vt) {
  const int w = blockIdx.x * 4 + (threadIdx.x >> 6);
  const int lane = threadIdx.x & 63;
  const int row = w / 24, unit = w % 24;  // row = b*S + s
  const int b = row >> 11, s = row & 2047;
  float x = b2f(qkv[(size_t)row * 1536 + unit * 64 + lane]);
  if (unit >= 20) {  // V head: transpose store, no norm/rope
    int hv = unit - 20;
    Vt[((size_t)(b * NKV + hv) * HD + lane) * S_LEN + s] = f2b(x);
    return;
  }
  const bool isq = unit < 16;
  const int h = isq ? unit : unit - 16;
  float ss = x * x;
  ss += __shfl_xor(ss, 1);
  ss += __shfl_xor(ss, 2);
  ss += __shfl_xor(ss, 4);
  ss += __shfl_xor(ss, 8);
  ss += __shfl_xor(ss, 16);
  ss += __shfl_xor(ss, 32);
  float r = rsqrtf(ss * (1.0f / 64.0f) + 1e-6f);
  float xn = x * r * (isq ? qw[lane] : kw[lane]);
  const int p = pos_ids[row];
  const float c = cosT[p * 64 + lane];
  const float sn = sinT[p * 64 + lane];
  float partner = __shfl_xor(xn, 32);
  float out = xn * c + (lane < 32 ? -partner : partner) * sn;
  if (isq) Qn[((size_t)(b * NH + h) * S_LEN + s) * HD + lane] = f2b(out);
  else     Kn[((size_t)(b * NKV + h) * S_LEN + s) * HD + lane] = f2b(out);
}

// ---------------- flash attention (causal, GQA 4:1) ----------------
// grid: (S/64 q-tiles, B*NH). block: 4 waves; wave w owns 16 q rows.
__global__ __launch_bounds__(256) void attn_kernel(const u16* __restrict__ Qn,
                                                   const u16* __restrict__ Kn,
                                                   const u16* __restrict__ Vt,
                                                   u16* __restrict__ ctx) {
  const int qt = blockIdx.x, bh = blockIdx.y;
  const int b = bh >> 4, h = bh & 15;
  const int hkv = h >> 2;
  const u16* Q = Qn + (size_t)bh * S_LEN * HD;
  const u16* K = Kn + (size_t)(b * NKV + hkv) * S_LEN * HD;
  const u16* V = Vt + (size_t)(b * NKV + hkv) * HD * S_LEN;
  const int wid = threadIdx.x >> 6, lane = threadIdx.x & 63;
  const int fr = lane & 15, fg = lane >> 4;
  const int q0 = qt * 64 + wid * 16;
  __shared__ u16 Pt[4][16][64];

  short8 qa[2];
#pragma unroll
  for (int c = 0; c < 2; ++c)
    qa[c] = *reinterpret_cast<const short8*>(&Q[(size_t)(q0 + fr) * HD + c * 32 + fg * 8]);

  f32x4 o[4] = {};
  float m[4], l[4];
#pragma unroll
  for (int j = 0; j < 4; ++j) { m[j] = -3.0e38f; l[j] = 0.0f; }

  for (int kt = 0; kt <= qt; ++kt) {
    const int kv0 = kt * 64;
    f32x4 s[4] = {};
#pragma unroll
    for (int c = 0; c < 2; ++c)
#pragma unroll
      for (int n = 0; n < 4; ++n) {
        short8 kb = *reinterpret_cast<const short8*>(
            &K[(size_t)(kv0 + n * 16 + fr) * HD + c * 32 + fg * 8]);
        s[n] = __builtin_amdgcn_mfma_f32_16x16x32_bf16(qa[c], kb, s[n], 0, 0, 0);
      }
    // scale + causal mask (D layout: row=(fg*4+j), col=n*16+fr)
#pragma unroll
    for (int n = 0; n < 4; ++n)
#pragma unroll
      for (int j = 0; j < 4; ++j) {
        int colk = kv0 + n * 16 + fr;
        int rowq = q0 + fg * 4 + j;
        float v = s[n][j] * 0.125f;
        s[n][j] = (colk <= rowq) ? v : -1.0e30f;
      }
    float alpha[4];
#pragma unroll
    for (int j = 0; j < 4; ++j) {
      float t = fmaxf(fmaxf(s[0][j], s[1][j]), fmaxf(s[2][j], s[3][j]));
      t = fmaxf(t, __shfl_xor(t, 1));
      t = fmaxf(t, __shfl_xor(t, 2));
      t = fmaxf(t, __shfl_xor(t, 4));
      t = fmaxf(t, __shfl_xor(t, 8));
      float mn = fmaxf(m[j], t);
      alpha[j] = __expf(m[j] - mn);
      m[j] = mn;
    }
#pragma unroll
    for (int n = 0; n < 4; ++n)
#pragma unroll
      for (int j = 0; j < 4; ++j)
        s[n][j] = __expf(s[n][j] - m[j]);
    float psum[4];
#pragma unroll
    for (int j = 0; j < 4; ++j) {
      float t = s[0][j] + s[1][j] + s[2][j] + s[3][j];
      t += __shfl_xor(t, 1);
      t += __shfl_xor(t, 2);
      t += __shfl_xor(t, 4);
      t += __shfl_xor(t, 8);
      psum[j] = t;
    }
    __syncthreads();  // previous iteration's Pt reads done before overwrite
#pragma unroll
    for (int n = 0; n < 4; ++n)
#pragma unroll
      for (int j = 0; j < 4; ++j)
        Pt[wid][fg * 4 + j][n * 16 + fr] = f2b(s[n][j]);
    __syncthreads();  // Pt writes visible
#pragma unroll
    for (int j = 0; j < 4; ++j) l[j] = l[j] * alpha[j] + psum[j];
#pragma unroll
    for (int dn = 0; dn < 4; ++dn)
#pragma unroll
      for (int j = 0; j < 4; ++j)
        o[dn][j] *= alpha[j];
    short8 pa[2];
#pragma unroll
    for (int c = 0; c < 2; ++c)
      pa[c] = *reinterpret_cast<const short8*>(&Pt[wid][fr][c * 32 + fg * 8]);
#pragma unroll
    for (int c = 0; c < 2; ++c)
#pragma unroll
      for (int dn = 0; dn < 4; ++dn) {
        short8 vb = *reinterpret_cast<const short8*>(
            &V[(size_t)(dn * 16 + fr) * S_LEN + kv0 + c * 32 + fg * 8]);
        o[dn] = __builtin_amdgcn_mfma_f32_16x16x32_bf16(pa[c], vb, o[dn], 0, 0, 0);
      }
  }
  float inv[4];
#pragma unroll
  for (int j = 0; j < 4; ++j) inv[j] = 1.0f / l[j];
#pragma unroll
  for (int dn = 0; dn < 4; ++dn)
#pragma unroll
    for (int j = 0; j < 4; ++j) {
      size_t row = (size_t)b * S_LEN + q0 + fg * 4 + j;
      ctx[row * (NH * HD) + h * HD + dn * 16 + fr] = f2b(o[dn][j] * inv[j]);
    }
}

extern "C" void kernel_launch(void* const* d_in, const int* in_sizes, int n_in,
                              void* d_out, int out_size, void* d_ws, size_t ws_size,
                              hipStream_t stream) {
  const float* hidden = (const float*)d_in[0];
  const float* cosT   = (const float*)d_in[1];
  const float* sinT   = (const float*)d_in[2];
  const int*   pos    = (const int*)d_in[3];
  // d_in[4] attention_mask: causal tril, applied analytically in attn_kernel
  const float* Wq = (const float*)d_in[5];
  const float* Wk = (const float*)d_in[6];
  const float* Wv = (const float*)d_in[7];
  const float* Wo = (const float*)d_in[8];
  const float* qw = (const float*)d_in[9];
  const float* kw = (const float*)d_in[10];

  char* p = (char*)d_ws;
  u16* hb   = (u16*)p; p += (size_t)4096 * 1024 * 2;   // hidden bf16
  u16* wqkv = (u16*)p; p += (size_t)1536 * 1024 * 2;   // [Wq;Wk;Wv] bf16
  u16* wob  = (u16*)p; p += (size_t)1024 * 1024 * 2;   // Wo bf16
  u16* qkvr = (u16*)p; p += (size_t)4096 * 1536 * 2;   // qkv projections bf16
  u16* qn   = (u16*)p; p += (size_t)(NH * 2) * S_LEN * HD * 2;   // Q normed+roped
  u16* kn   = (u16*)p; p += (size_t)(NKV * 2) * S_LEN * HD * 2;  // K normed+roped
  u16* vt   = (u16*)p; p += (size_t)(NKV * 2) * HD * S_LEN * 2;  // V transposed
  u16* ctx  = (u16*)p; p += (size_t)4096 * 1024 * 2;   // attention output bf16

  f2b_kernel<<<4194304 / 256, 256, 0, stream>>>(hidden, hb, 4194304);
  f2b_kernel<<<1048576 / 256, 256, 0, stream>>>(Wq, wqkv, 1048576);
  f2b_kernel<<<262144 / 256, 256, 0, stream>>>(Wk, wqkv + 1048576, 262144);
  f2b_kernel<<<262144 / 256, 256, 0, stream>>>(Wv, wqkv + 1310720, 262144);
  f2b_kernel<<<1048576 / 256, 256, 0, stream>>>(Wo, wob, 1048576);

  // QKV projection: [4096 x 1536] = hb [4096x1024] * wqkv^T
  gemm_bt<1><<<dim3(32, 12), 256, 0, stream>>>(hb, wqkv, qkvr, 4096, 1536, 1024);

  // RMSNorm + RoPE + layouts (B*S*(NH+2*NKV) = 98304 waves)
  normrope<<<24576, 256, 0, stream>>>(qkvr, pos, cosT, sinT, qw, kw, qn, kn, vt);

  // attention: grid (q-tiles, B*NH)
  attn_kernel<<<dim3(S_LEN / 64, 2 * NH), 256, 0, stream>>>(qn, kn, vt, ctx);

  // output projection -> fp32 d_out
  gemm_bt<0><<<dim3(32, 8), 256, 0, stream>>>(ctx, wob, d_out, 4096, 1024, 1024);
}

// Round 2
// 339.253 us; speedup vs baseline: 1.2127x; 1.2127x over previous
//
#include <hip/hip_runtime.h>
#include <stdint.h>

#define S_LEN 2048
#define HIDDEN 1024
#define NH 16
#define NKV 4
#define HD 64

typedef unsigned short u16;
typedef __attribute__((ext_vector_type(8))) short short8;
typedef __attribute__((ext_vector_type(4))) float f32x4;

__device__ __forceinline__ u16 f2b(float f) {
  uint32_t u = __float_as_uint(f);
  uint32_t r = u + 0x7fffu + ((u >> 16) & 1u);
  return (u16)(r >> 16);
}
__device__ __forceinline__ float b2f(u16 b) {
  return __uint_as_float(((uint32_t)b) << 16);
}
__device__ __forceinline__ void gll16(const void* g, void* l) {
  __builtin_amdgcn_global_load_lds(
      (const __attribute__((address_space(1))) uint32_t*)g,
      (__attribute__((address_space(3))) uint32_t*)l, 16, 0, 0);
}

// ---------------- fp32 -> bf16 convert ----------------
__global__ __launch_bounds__(256) void f2b_kernel(const float* __restrict__ src,
                                                  u16* __restrict__ dst, int n) {
  int i = blockIdx.x * 256 + threadIdx.x;
  if (i < n) dst[i] = f2b(src[i]);
}

// ---------------- bf16 GEMM: C = A * B^T (A:[M][K], B:[N][K]) ----------------
// 128x128 tile, BK=32, 4 waves (2x2 of 64x64), mfma 16x16x32 bf16,
// staging via global_load_lds width=16 (m97 structure).
template <int OUT_BF16>
__global__ __launch_bounds__(256) void gemm_bt(const u16* __restrict__ A,
                                               const u16* __restrict__ B,
                                               void* __restrict__ Cv,
                                               int M, int N, int K) {
  __shared__ u16 As[128][32];
  __shared__ u16 Bs[128][32];
  const int tid = threadIdx.x;
  const int wid = tid >> 6, lane = tid & 63;
  const int fr = lane & 15, fg = lane >> 4;
  const int m0 = blockIdx.x * 128, n0 = blockIdx.y * 128;
  const int wr = wid >> 1, wc = wid & 1;
  const int srow = lane >> 2, scol = (lane & 3) << 3;
  f32x4 acc[4][4] = {};

  for (int k0 = 0; k0 < K; k0 += 32) {
    __syncthreads();
#pragma unroll
    for (int i = 0; i < 2; ++i) {
      const int c = wid + i * 4;  // chunk: 16 rows = 1KB = one wave-instr
      gll16(&A[(size_t)(m0 + c * 16 + srow) * K + k0 + scol], &As[c * 16][0]);
      gll16(&B[(size_t)(n0 + c * 16 + srow) * K + k0 + scol], &Bs[c * 16][0]);
    }
    __syncthreads();  // compiler drains vmcnt before s_barrier
    short8 a[4], b[4];
#pragma unroll
    for (int i = 0; i < 4; ++i) {
      a[i] = *reinterpret_cast<const short8*>(&As[wr * 64 + i * 16 + fr][fg * 8]);
      b[i] = *reinterpret_cast<const short8*>(&Bs[wc * 64 + i * 16 + fr][fg * 8]);
    }
#pragma unroll
    for (int i = 0; i < 4; ++i)
#pragma unroll
      for (int j = 0; j < 4; ++j)
        acc[i][j] = __builtin_amdgcn_mfma_f32_16x16x32_bf16(a[i], b[j], acc[i][j], 0, 0, 0);
  }

  const int rb = fg * 4;
#pragma unroll
  for (int i = 0; i < 4; ++i)
#pragma unroll
    for (int j = 0; j < 4; ++j) {
      const int row0 = m0 + wr * 64 + i * 16 + rb;
      const int col = n0 + wc * 64 + j * 16 + fr;
#pragma unroll
      for (int r = 0; r < 4; ++r) {
        size_t idx = (size_t)(row0 + r) * N + col;
        if (OUT_BF16) ((u16*)Cv)[idx] = f2b(acc[i][j][r]);
        else          ((float*)Cv)[idx] = acc[i][j][r];
      }
    }
}

// ---------------- per-head RMSNorm + RoPE (Q,K only) ----------------
__global__ __launch_bounds__(256) void normrope(const u16* __restrict__ qkv,
                                                const int* __restrict__ pos_ids,
                                                const float* __restrict__ cosT,
                                                const float* __restrict__ sinT,
                                                const float* __restrict__ qw,
                                                const float* __restrict__ kw,
                                                u16* __restrict__ Qn,
                                                u16* __restrict__ Kn) {
  const int w = blockIdx.x * 4 + (threadIdx.x >> 6);
  const int lane = threadIdx.x & 63;
  const int row = w / 20, unit = w % 20;  // row = b*S + s
  const int b = row >> 11, s = row & 2047;
  float x = b2f(qkv[(size_t)row * 1536 + unit * 64 + lane]);
  const bool isq = unit < 16;
  const int h = isq ? unit : unit - 16;
  float ss = x * x;
  ss += __shfl_xor(ss, 1);
  ss += __shfl_xor(ss, 2);
  ss += __shfl_xor(ss, 4);
  ss += __shfl_xor(ss, 8);
  ss += __shfl_xor(ss, 16);
  ss += __shfl_xor(ss, 32);
  float r = rsqrtf(ss * (1.0f / 64.0f) + 1e-6f);
  float xn = x * r * (isq ? qw[lane] : kw[lane]);
  const int p = pos_ids[row];
  const float c = cosT[p * 64 + lane];
  const float sn = sinT[p * 64 + lane];
  float partner = __shfl_xor(xn, 32);
  float out = xn * c + (lane < 32 ? -partner : partner) * sn;
  if (isq) Qn[((size_t)(b * NH + h) * S_LEN + s) * HD + lane] = f2b(out);
  else     Kn[((size_t)(b * NKV + h) * S_LEN + s) * HD + lane] = f2b(out);
}

// ---------------- V transpose via LDS tiles ----------------
// qkvr cols 1280..1535 hold V [b][s][hv][64] -> Vt [b*NKV+hv][64][S]
__global__ __launch_bounds__(256) void vtrans(const u16* __restrict__ qkv,
                                              u16* __restrict__ Vt) {
  const int s0 = blockIdx.x * 64;
  const int b = blockIdx.y >> 2, hv = blockIdx.y & 3;
  __shared__ u16 t[64][72];
  const int tid = threadIdx.x;
  const int r = tid >> 2, cq = (tid & 3) << 4;
#pragma unroll
  for (int i = 0; i < 2; ++i)
    *reinterpret_cast<short8*>(&t[r][cq + i * 8]) =
        *reinterpret_cast<const short8*>(
            &qkv[(size_t)(b * S_LEN + s0 + r) * 1536 + 1280 + hv * 64 + cq + i * 8]);
  __syncthreads();
  const int d = tid >> 2, sq = (tid & 3) << 4;
#pragma unroll
  for (int i = 0; i < 2; ++i) {
    u16 tmp[8];
#pragma unroll
    for (int k = 0; k < 8; ++k) tmp[k] = t[sq + i * 8 + k][d];
    *reinterpret_cast<short8*>(
        &Vt[((size_t)(b * NKV + hv) * HD + d) * S_LEN + s0 + sq + i * 8]) =
        *reinterpret_cast<short8*>(tmp);
  }
}

// ---------------- flash attention (causal, GQA 4:1, kv-split) ----------------
// grid: (S/16 q-tiles, B*NH). block: 4 waves; ALL waves share the 16 q-rows,
// wave w handles kv-tiles {w, w+4, ...}; merge (m,l,o) across waves at end.
__global__ __launch_bounds__(256) void attn_kernel(const u16* __restrict__ Qn,
                                                   const u16* __restrict__ Kn,
                                                   const u16* __restrict__ Vt,
                                                   u16* __restrict__ ctx) {
  const int bh = blockIdx.y;
  const int b = bh >> 4, h = bh & 15;
  const int hkv = h >> 2;
  const u16* Q = Qn + (size_t)bh * S_LEN * HD;
  const u16* K = Kn + (size_t)(b * NKV + hkv) * S_LEN * HD;
  const u16* V = Vt + (size_t)(b * NKV + hkv) * HD * S_LEN;
  const int wid = threadIdx.x >> 6, lane = threadIdx.x & 63;
  const int fr = lane & 15, fg = lane >> 4;
  const int q0 = blockIdx.x * 16;
  const int diag = q0 >> 6;  // last kv-tile index
  __shared__ u16 Pt[4][16][64];     // XOR-swizzled: col ^ ((row&7)<<3)
  __shared__ float Om[4][16][64];
  __shared__ float Ml[4][16], Ll[4][16];

  short8 qa[2];
#pragma unroll
  for (int c = 0; c < 2; ++c)
    qa[c] = *reinterpret_cast<const short8*>(&Q[(size_t)(q0 + fr) * HD + c * 32 + fg * 8]);

  f32x4 o[4] = {};
  float m[4], l[4];
#pragma unroll
  for (int j = 0; j < 4; ++j) { m[j] = -3.0e38f; l[j] = 0.0f; }

  for (int kt = wid; kt <= diag; kt += 4) {
    const int kv0 = kt * 64;
    f32x4 s[4] = {};
#pragma unroll
    for (int c = 0; c < 2; ++c)
#pragma unroll
      for (int n = 0; n < 4; ++n) {
        short8 kb = *reinterpret_cast<const short8*>(
            &K[(size_t)(kv0 + n * 16 + fr) * HD + c * 32 + fg * 8]);
        s[n] = __builtin_amdgcn_mfma_f32_16x16x32_bf16(qa[c], kb, s[n], 0, 0, 0);
      }
    // scale + causal mask (D layout: row=fg*4+j, col=n*16+fr)
#pragma unroll
    for (int n = 0; n < 4; ++n)
#pragma unroll
      for (int j = 0; j < 4; ++j) {
        int colk = kv0 + n * 16 + fr;
        int rowq = q0 + fg * 4 + j;
        float v = s[n][j] * 0.125f;
        s[n][j] = (colk <= rowq) ? v : -1.0e30f;
      }
    float alpha[4];
#pragma unroll
    for (int j = 0; j < 4; ++j) {
      float t = fmaxf(fmaxf(s[0][j], s[1][j]), fmaxf(s[2][j], s[3][j]));
      t = fmaxf(t, __shfl_xor(t, 1));
      t = fmaxf(t, __shfl_xor(t, 2));
      t = fmaxf(t, __shfl_xor(t, 4));
      t = fmaxf(t, __shfl_xor(t, 8));
      float mn = fmaxf(m[j], t);
      alpha[j] = __expf(m[j] - mn);
      m[j] = mn;
    }
#pragma unroll
    for (int n = 0; n < 4; ++n)
#pragma unroll
      for (int j = 0; j < 4; ++j)
        s[n][j] = __expf(s[n][j] - m[j]);
    float psum[4];
#pragma unroll
    for (int j = 0; j < 4; ++j) {
      float t = s[0][j] + s[1][j] + s[2][j] + s[3][j];
      t += __shfl_xor(t, 1);
      t += __shfl_xor(t, 2);
      t += __shfl_xor(t, 4);
      t += __shfl_xor(t, 8);
      psum[j] = t;
    }
    // P -> LDS (wave-private slice, XOR swizzle; no block barrier needed)
#pragma unroll
    for (int n = 0; n < 4; ++n)
#pragma unroll
      for (int j = 0; j < 4; ++j) {
        const int row = fg * 4 + j;
        Pt[wid][row][(n * 16 + fr) ^ ((row & 7) << 3)] = f2b(s[n][j]);
      }
#pragma unroll
    for (int j = 0; j < 4; ++j) l[j] = l[j] * alpha[j] + psum[j];
#pragma unroll
    for (int dn = 0; dn < 4; ++dn)
#pragma unroll
      for (int j = 0; j < 4; ++j)
        o[dn][j] *= alpha[j];
    short8 pa[2];
#pragma unroll
    for (int c = 0; c < 2; ++c)
      pa[c] = *reinterpret_cast<const short8*>(
          &Pt[wid][fr][(c * 32 + fg * 8) ^ ((fr & 7) << 3)]);
#pragma unroll
    for (int c = 0; c < 2; ++c)
#pragma unroll
      for (int dn = 0; dn < 4; ++dn) {
        short8 vb = *reinterpret_cast<const short8*>(
            &V[(size_t)(dn * 16 + fr) * S_LEN + kv0 + c * 32 + fg * 8]);
        o[dn] = __builtin_amdgcn_mfma_f32_16x16x32_bf16(pa[c], vb, o[dn], 0, 0, 0);
      }
  }

  // publish per-wave state
  if (fr == 0) {
#pragma unroll
    for (int j = 0; j < 4; ++j) {
      Ml[wid][fg * 4 + j] = m[j];
      Ll[wid][fg * 4 + j] = l[j];
    }
  }
#pragma unroll
  for (int dn = 0; dn < 4; ++dn)
#pragma unroll
    for (int j = 0; j < 4; ++j)
      Om[wid][fg * 4 + j][dn * 16 + fr] = o[dn][j];
  __syncthreads();

  // merge: thread t -> row r = t>>4, cols c0..c0+3
  const int t = threadIdx.x;
  const int r = t >> 4, c0 = (t & 15) << 2;
  float M = fmaxf(fmaxf(Ml[0][r], Ml[1][r]), fmaxf(Ml[2][r], Ml[3][r]));
  float L = 0.0f;
  float acc[4] = {0.0f, 0.0f, 0.0f, 0.0f};
#pragma unroll
  for (int w = 0; w < 4; ++w) {
    float ww = __expf(Ml[w][r] - M);
    L += Ll[w][r] * ww;
#pragma unroll
    for (int c = 0; c < 4; ++c) acc[c] += Om[w][r][c0 + c] * ww;
  }
  float invL = 1.0f / L;
  const size_t row = (size_t)b * S_LEN + q0 + r;
#pragma unroll
  for (int c = 0; c < 4; ++c)
    ctx[row * (NH * HD) + h * HD + c0 + c] = f2b(acc[c] * invL);
}

extern "C" void kernel_launch(void* const* d_in, const int* in_sizes, int n_in,
                              void* d_out, int out_size, void* d_ws, size_t ws_size,
                              hipStream_t stream) {
  const float* hidden = (const float*)d_in[0];
  const float* cosT   = (const float*)d_in[1];
  const float* sinT   = (const float*)d_in[2];
  const int*   pos    = (const int*)d_in[3];
  // d_in[4] attention_mask: causal tril, applied analytically in attn_kernel
  const float* Wq = (const float*)d_in[5];
  const float* Wk = (const float*)d_in[6];
  const float* Wv = (const float*)d_in[7];
  const float* Wo = (const float*)d_in[8];
  const float* qw = (const float*)d_in[9];
  const float* kw = (const float*)d_in[10];

  char* p = (char*)d_ws;
  u16* hb   = (u16*)p; p += (size_t)4096 * 1024 * 2;   // hidden bf16
  u16* wqkv = (u16*)p; p += (size_t)1536 * 1024 * 2;   // [Wq;Wk;Wv] bf16
  u16* wob  = (u16*)p; p += (size_t)1024 * 1024 * 2;   // Wo bf16
  u16* qkvr = (u16*)p; p += (size_t)4096 * 1536 * 2;   // qkv projections bf16
  u16* qn   = (u16*)p; p += (size_t)(NH * 2) * S_LEN * HD * 2;   // Q normed+roped
  u16* kn   = (u16*)p; p += (size_t)(NKV * 2) * S_LEN * HD * 2;  // K normed+roped
  u16* vt   = (u16*)p; p += (size_t)(NKV * 2) * HD * S_LEN * 2;  // V transposed
  u16* ctx  = (u16*)p; p += (size_t)4096 * 1024 * 2;   // attention output bf16

  f2b_kernel<<<4194304 / 256, 256, 0, stream>>>(hidden, hb, 4194304);
  f2b_kernel<<<1048576 / 256, 256, 0, stream>>>(Wq, wqkv, 1048576);
  f2b_kernel<<<262144 / 256, 256, 0, stream>>>(Wk, wqkv + 1048576, 262144);
  f2b_kernel<<<262144 / 256, 256, 0, stream>>>(Wv, wqkv + 1310720, 262144);
  f2b_kernel<<<1048576 / 256, 256, 0, stream>>>(Wo, wob, 1048576);

  // QKV projection: [4096 x 1536] = hb [4096x1024] * wqkv^T
  gemm_bt<1><<<dim3(32, 12), 256, 0, stream>>>(hb, wqkv, qkvr, 4096, 1536, 1024);

  // RMSNorm + RoPE for Q,K (4096 rows x 20 head-units)
  normrope<<<20480, 256, 0, stream>>>(qkvr, pos, cosT, sinT, qw, kw, qn, kn);
  // V transpose
  vtrans<<<dim3(32, 8), 256, 0, stream>>>(qkvr, vt);

  // attention: grid (16-row q-tiles, B*NH), kv-split across 4 waves
  attn_kernel<<<dim3(S_LEN / 16, 2 * NH), 256, 0, stream>>>(qn, kn, vt, ctx);

  // output projection -> fp32 d_out
  gemm_bt<0><<<dim3(32, 8), 256, 0, stream>>>(ctx, wob, d_out, 4096, 1024, 1024);
}

// Round 3
// 256.591 us; speedup vs baseline: 1.6034x; 1.3222x over previous
//
#include <hip/hip_runtime.h>
#include <stdint.h>

#define S_LEN 2048
#define HIDDEN 1024
#define NH 16
#define NKV 4
#define HD 64

typedef unsigned short u16;
typedef __attribute__((ext_vector_type(8))) short short8;
typedef __attribute__((ext_vector_type(4))) float f32x4;
typedef __attribute__((ext_vector_type(16))) float f32x16;
typedef __attribute__((ext_vector_type(4))) uint32_t u32x4;

__device__ __forceinline__ u16 f2b(float f) {
  uint32_t u = __float_as_uint(f);
  uint32_t r = u + 0x7fffu + ((u >> 16) & 1u);
  return (u16)(r >> 16);
}
__device__ __forceinline__ float b2f(u16 b) {
  return __uint_as_float(((uint32_t)b) << 16);
}
__device__ __forceinline__ void gll16(const void* g, void* l) {
  __builtin_amdgcn_global_load_lds(
      (const __attribute__((address_space(1))) uint32_t*)g,
      (__attribute__((address_space(3))) uint32_t*)l, 16, 0, 0);
}

// ---------------- fp32 -> bf16 convert (8 elem/thread, vectorized) ----------
__global__ __launch_bounds__(256) void f2b_kernel(const float* __restrict__ src,
                                                  u16* __restrict__ dst, int n8) {
  int i = blockIdx.x * 256 + threadIdx.x;
  if (i >= n8) return;
  f32x4 a = *reinterpret_cast<const f32x4*>(&src[(size_t)i * 8]);
  f32x4 b = *reinterpret_cast<const f32x4*>(&src[(size_t)i * 8 + 4]);
  short8 t;
#pragma unroll
  for (int k = 0; k < 4; ++k) t[k] = (short)f2b(a[k]);
#pragma unroll
  for (int k = 0; k < 4; ++k) t[4 + k] = (short)f2b(b[k]);
  *reinterpret_cast<short8*>(&dst[(size_t)i * 8]) = t;
}

// ---------------- bf16 GEMM: C = A * B^T (A:[M][K], B:[N][K]) ----------------
template <int OUT_BF16>
__global__ __launch_bounds__(256) void gemm_bt(const u16* __restrict__ A,
                                               const u16* __restrict__ B,
                                               void* __restrict__ Cv,
                                               int M, int N, int K) {
  __shared__ u16 As[128][32];
  __shared__ u16 Bs[128][32];
  const int tid = threadIdx.x;
  const int wid = tid >> 6, lane = tid & 63;
  const int fr = lane & 15, fg = lane >> 4;
  const int m0 = blockIdx.x * 128, n0 = blockIdx.y * 128;
  const int wr = wid >> 1, wc = wid & 1;
  const int srow = lane >> 2, scol = (lane & 3) << 3;
  f32x4 acc[4][4] = {};

  for (int k0 = 0; k0 < K; k0 += 32) {
    __syncthreads();
#pragma unroll
    for (int i = 0; i < 2; ++i) {
      const int c = wid + i * 4;
      gll16(&A[(size_t)(m0 + c * 16 + srow) * K + k0 + scol], &As[c * 16][0]);
      gll16(&B[(size_t)(n0 + c * 16 + srow) * K + k0 + scol], &Bs[c * 16][0]);
    }
    __syncthreads();
    short8 a[4], b[4];
#pragma unroll
    for (int i = 0; i < 4; ++i) {
      a[i] = *reinterpret_cast<const short8*>(&As[wr * 64 + i * 16 + fr][fg * 8]);
      b[i] = *reinterpret_cast<const short8*>(&Bs[wc * 64 + i * 16 + fr][fg * 8]);
    }
#pragma unroll
    for (int i = 0; i < 4; ++i)
#pragma unroll
      for (int j = 0; j < 4; ++j)
        acc[i][j] = __builtin_amdgcn_mfma_f32_16x16x32_bf16(a[i], b[j], acc[i][j], 0, 0, 0);
  }

  const int rb = fg * 4;
#pragma unroll
  for (int i = 0; i < 4; ++i)
#pragma unroll
    for (int j = 0; j < 4; ++j) {
      const int row0 = m0 + wr * 64 + i * 16 + rb;
      const int col = n0 + wc * 64 + j * 16 + fr;
#pragma unroll
      for (int r = 0; r < 4; ++r) {
        size_t idx = (size_t)(row0 + r) * N + col;
        if (OUT_BF16) ((u16*)Cv)[idx] = f2b(acc[i][j][r]);
        else          ((float*)Cv)[idx] = acc[i][j][r];
      }
    }
}

// ---------------- per-head RMSNorm + RoPE (Q,K only) ----------------
__global__ __launch_bounds__(256) void normrope(const u16* __restrict__ qkv,
                                                const int* __restrict__ pos_ids,
                                                const float* __restrict__ cosT,
                                                const float* __restrict__ sinT,
                                                const float* __restrict__ qw,
                                                const float* __restrict__ kw,
                                                u16* __restrict__ Qn,
                                                u16* __restrict__ Kn) {
  const int w = blockIdx.x * 4 + (threadIdx.x >> 6);
  const int lane = threadIdx.x & 63;
  const int row = w / 20, unit = w % 20;
  const int b = row >> 11, s = row & 2047;
  float x = b2f(qkv[(size_t)row * 1536 + unit * 64 + lane]);
  const bool isq = unit < 16;
  const int h = isq ? unit : unit - 16;
  float ss = x * x;
  ss += __shfl_xor(ss, 1);
  ss += __shfl_xor(ss, 2);
  ss += __shfl_xor(ss, 4);
  ss += __shfl_xor(ss, 8);
  ss += __shfl_xor(ss, 16);
  ss += __shfl_xor(ss, 32);
  float r = rsqrtf(ss * (1.0f / 64.0f) + 1e-6f);
  float xn = x * r * (isq ? qw[lane] : kw[lane]);
  const int p = pos_ids[row];
  const float c = cosT[p * 64 + lane];
  const float sn = sinT[p * 64 + lane];
  float partner = __shfl_xor(xn, 32);
  float out = xn * c + (lane < 32 ? -partner : partner) * sn;
  if (isq) Qn[((size_t)(b * NH + h) * S_LEN + s) * HD + lane] = f2b(out);
  else     Kn[((size_t)(b * NKV + h) * S_LEN + s) * HD + lane] = f2b(out);
}

// ---------------- V transpose via LDS tiles ----------------
__global__ __launch_bounds__(256) void vtrans(const u16* __restrict__ qkv,
                                              u16* __restrict__ Vt) {
  const int s0 = blockIdx.x * 64;
  const int b = blockIdx.y >> 2, hv = blockIdx.y & 3;
  __shared__ u16 t[64][72];
  const int tid = threadIdx.x;
  const int r = tid >> 2, cq = (tid & 3) << 4;
#pragma unroll
  for (int i = 0; i < 2; ++i)
    *reinterpret_cast<short8*>(&t[r][cq + i * 8]) =
        *reinterpret_cast<const short8*>(
            &qkv[(size_t)(b * S_LEN + s0 + r) * 1536 + 1280 + hv * 64 + cq + i * 8]);
  __syncthreads();
  const int d = tid >> 2, sq = (tid & 3) << 4;
#pragma unroll
  for (int i = 0; i < 2; ++i) {
    u16 tmp[8];
#pragma unroll
    for (int k = 0; k < 8; ++k) tmp[k] = t[sq + i * 8 + k][d];
    *reinterpret_cast<short8*>(
        &Vt[((size_t)(b * NKV + hv) * HD + d) * S_LEN + s0 + sq + i * 8]) =
        *reinterpret_cast<short8*>(tmp);
  }
}

// ---------------- flash attention: swapped QK^T, 32x32x16 MFMA --------------
// grid (16, B*NH); block = 4 waves; wave w owns q-tile {j, 31-j, 32+j, 63-j}[w]
// (32 q rows). Per kv-32 tile: S^T = mfma(K,Q); softmax lane-local (1 shfl32
// per reduce); P packed to bf16 in-register (cvt_pk + shfl32) feeds PV as the
// B operand with V^T as A. No barriers, no inter-wave merge.
__global__ __launch_bounds__(256) void attn_kernel(const u16* __restrict__ Qn,
                                                   const u16* __restrict__ Kn,
                                                   const u16* __restrict__ Vt,
                                                   u16* __restrict__ ctx) {
  const int bh = blockIdx.y;
  const int b = bh >> 4, h = bh & 15, hkv = h >> 2;
  const u16* Q = Qn + (size_t)bh * S_LEN * HD;
  const u16* K = Kn + (size_t)(b * NKV + hkv) * S_LEN * HD;
  const u16* V = Vt + (size_t)(b * NKV + hkv) * HD * S_LEN;
  const int wid = threadIdx.x >> 6, lane = threadIdx.x & 63;
  const int col = lane & 31, hi = lane >> 5;
  const int j = blockIdx.x;
  int qt;
  if (wid == 0) qt = j;
  else if (wid == 1) qt = 31 - j;
  else if (wid == 2) qt = 32 + j;
  else qt = 63 - j;
  const int q0 = qt * 32;

  short8 qf[4];
#pragma unroll
  for (int d = 0; d < 4; ++d)
    qf[d] = *reinterpret_cast<const short8*>(&Q[(size_t)(q0 + col) * HD + d * 16 + hi * 8]);

  f32x16 o0 = {}, o1 = {};
  float m = -3.0e38f, l = 0.0f;
  const float SC = 0.125f;  // 1/sqrt(64)

  for (int kt = 0; kt <= qt; ++kt) {
    const int kv0 = kt * 32;
    f32x16 s = {};
#pragma unroll
    for (int d = 0; d < 4; ++d) {
      short8 kf = *reinterpret_cast<const short8*>(
          &K[(size_t)(kv0 + col) * HD + d * 16 + hi * 8]);
      s = __builtin_amdgcn_mfma_f32_32x32x16_bf16(kf, qf[d], s, 0, 0, 0);
    }
    if (kt == qt) {  // diagonal tile: mask kv > q (kv rel = (r&3)+8*(r>>2)+4*hi)
#pragma unroll
      for (int r = 0; r < 16; ++r) {
        int kvr = (r & 3) + 8 * (r >> 2) + 4 * hi;
        s[r] = (kvr <= col) ? s[r] : -3.0e38f;
      }
    }
    // row max: in-reg tree + one cross-half exchange
    float t8[8];
#pragma unroll
    for (int r = 0; r < 8; ++r) t8[r] = fmaxf(s[r], s[r + 8]);
#pragma unroll
    for (int r = 0; r < 4; ++r) t8[r] = fmaxf(t8[r], t8[r + 4]);
    float tm = fmaxf(fmaxf(t8[0], t8[1]), fmaxf(t8[2], t8[3]));
    tm = fmaxf(tm, __shfl_xor(tm, 32));
    // defer-max (T13): skip rescale unless max grew past e^8 headroom
    if (!__all(tm <= m + 64.0f)) {
      float mn = fmaxf(m, tm);
      float al = __expf((m - mn) * SC);
      m = mn;
      l *= al;
#pragma unroll
      for (int r = 0; r < 16; ++r) { o0[r] *= al; o1[r] *= al; }
    }
    const float mSC = m * SC;
    float p[16];
#pragma unroll
    for (int r = 0; r < 16; ++r) p[r] = __expf(s[r] * SC - mSC);
    float u8[8];
#pragma unroll
    for (int r = 0; r < 8; ++r) u8[r] = p[r] + p[r + 8];
#pragma unroll
    for (int r = 0; r < 4; ++r) u8[r] += u8[r + 4];
    float ps = (u8[0] + u8[1]) + (u8[2] + u8[3]);
    ps += __shfl_xor(ps, 32);
    l += ps;
    // pack P -> bf16 words; exchange halves; build PV B-fragments
    uint32_t w[8], x[8];
#pragma unroll
    for (int i = 0; i < 8; ++i) {
      uint32_t wo;
      asm("v_cvt_pk_bf16_f32 %0, %1, %2" : "=v"(wo) : "v"(p[2 * i]), "v"(p[2 * i + 1]));
      w[i] = wo;
    }
#pragma unroll
    for (int i = 0; i < 8; ++i) x[i] = (uint32_t)__shfl_xor((int)w[i], 32);
    u32x4 bw0 = {hi ? x[2] : w[0], hi ? x[3] : w[1], hi ? w[2] : x[0], hi ? w[3] : x[1]};
    u32x4 bw1 = {hi ? x[6] : w[4], hi ? x[7] : w[5], hi ? w[6] : x[4], hi ? w[7] : x[5]};
    short8 B0 = __builtin_bit_cast(short8, bw0);
    short8 B1 = __builtin_bit_cast(short8, bw1);
    // PV: O^T[d][q] += V^T[d][kv] * P^T[kv][q]
    short8 vf;
    vf = *reinterpret_cast<const short8*>(&V[(size_t)col * S_LEN + kv0 + hi * 8]);
    o0 = __builtin_amdgcn_mfma_f32_32x32x16_bf16(vf, B0, o0, 0, 0, 0);
    vf = *reinterpret_cast<const short8*>(&V[(size_t)col * S_LEN + kv0 + 16 + hi * 8]);
    o0 = __builtin_amdgcn_mfma_f32_32x32x16_bf16(vf, B1, o0, 0, 0, 0);
    vf = *reinterpret_cast<const short8*>(&V[(size_t)(32 + col) * S_LEN + kv0 + hi * 8]);
    o1 = __builtin_amdgcn_mfma_f32_32x32x16_bf16(vf, B0, o1, 0, 0, 0);
    vf = *reinterpret_cast<const short8*>(&V[(size_t)(32 + col) * S_LEN + kv0 + 16 + hi * 8]);
    o1 = __builtin_amdgcn_mfma_f32_32x32x16_bf16(vf, B1, o1, 0, 0, 0);
  }

  // epilogue: normalize, transpose O^T -> O via wave-private LDS, store
  const float invl = 1.0f / l;
  __shared__ __align__(16) u16 Tl[4][32][72];
#pragma unroll
  for (int r = 0; r < 16; ++r) {
    int dl = (r & 3) + 8 * (r >> 2) + 4 * hi;
    Tl[wid][col][dl] = f2b(o0[r] * invl);
    Tl[wid][col][32 + dl] = f2b(o1[r] * invl);
  }
  // lane: row = col, half = hi -> 32 contiguous u16
#pragma unroll
  for (int k2 = 0; k2 < 4; ++k2) {
    short8 vv = *reinterpret_cast<const short8*>(&Tl[wid][col][hi * 32 + k2 * 8]);
    *reinterpret_cast<short8*>(
        &ctx[((size_t)(b * S_LEN) + q0 + col) * (NH * HD) + h * HD + hi * 32 + k2 * 8]) = vv;
  }
}

extern "C" void kernel_launch(void* const* d_in, const int* in_sizes, int n_in,
                              void* d_out, int out_size, void* d_ws, size_t ws_size,
                              hipStream_t stream) {
  const float* hidden = (const float*)d_in[0];
  const float* cosT   = (const float*)d_in[1];
  const float* sinT   = (const float*)d_in[2];
  const int*   pos    = (const int*)d_in[3];
  // d_in[4] attention_mask: causal tril, applied analytically in attn_kernel
  const float* Wq = (const float*)d_in[5];
  const float* Wk = (const float*)d_in[6];
  const float* Wv = (const float*)d_in[7];
  const float* Wo = (const float*)d_in[8];
  const float* qw = (const float*)d_in[9];
  const float* kw = (const float*)d_in[10];

  char* p = (char*)d_ws;
  u16* hb   = (u16*)p; p += (size_t)4096 * 1024 * 2;
  u16* wqkv = (u16*)p; p += (size_t)1536 * 1024 * 2;
  u16* wob  = (u16*)p; p += (size_t)1024 * 1024 * 2;
  u16* qkvr = (u16*)p; p += (size_t)4096 * 1536 * 2;
  u16* qn   = (u16*)p; p += (size_t)(NH * 2) * S_LEN * HD * 2;
  u16* kn   = (u16*)p; p += (size_t)(NKV * 2) * S_LEN * HD * 2;
  u16* vt   = (u16*)p; p += (size_t)(NKV * 2) * HD * S_LEN * 2;
  u16* ctx  = (u16*)p; p += (size_t)4096 * 1024 * 2;

  f2b_kernel<<<4194304 / 2048, 256, 0, stream>>>(hidden, hb, 4194304 / 8);
  f2b_kernel<<<1048576 / 2048, 256, 0, stream>>>(Wq, wqkv, 1048576 / 8);
  f2b_kernel<<<262144 / 2048, 256, 0, stream>>>(Wk, wqkv + 1048576, 262144 / 8);
  f2b_kernel<<<262144 / 2048, 256, 0, stream>>>(Wv, wqkv + 1310720, 262144 / 8);
  f2b_kernel<<<1048576 / 2048, 256, 0, stream>>>(Wo, wob, 1048576 / 8);

  gemm_bt<1><<<dim3(32, 12), 256, 0, stream>>>(hb, wqkv, qkvr, 4096, 1536, 1024);

  normrope<<<20480, 256, 0, stream>>>(qkvr, pos, cosT, sinT, qw, kw, qn, kn);
  vtrans<<<dim3(32, 8), 256, 0, stream>>>(qkvr, vt);

  // attention: 16 blocks x (B*NH); each block = 4 equal-work q-tiles
  attn_kernel<<<dim3(16, 2 * NH), 256, 0, stream>>>(qn, kn, vt, ctx);

  gemm_bt<0><<<dim3(32, 8), 256, 0, stream>>>(ctx, wob, d_out, 4096, 1024, 1024);
}